// Round 6
// baseline (106.803 us; speedup 1.0000x reference)
//
#include <hip/hip_runtime.h>
#include <math.h>

#define NRES 4096
#define GRID 768                  // 3 blocks/CU exactly (48KB LDS cap)
#define HB_BLOCKS (NRES / 256)    // 16
#define PSTRIDE (GRID * 256)      // 196608

typedef float  f32x4 __attribute__((ext_vector_type(4)));
typedef int    i32x2 __attribute__((ext_vector_type(2)));

__device__ __forceinline__ float wave_sum(float v) {
#pragma unroll
    for (int off = 32; off > 0; off >>= 1) v += __shfl_down(v, off, 64);
    return v;
}

__device__ __forceinline__ float fsqrt(float x) { return __builtin_amdgcn_sqrtf(x); }

// 4 contact terms: one K float4 vs 4 LDS columns
__device__ __forceinline__ float c4(f32x4 kv, f32x4 cx, f32x4 cy, f32x4 cz,
                                    float xi, float yi, float zi, float s) {
    float dx, dy, dz, D, t;
#pragma unroll
    for (int e = 0; e < 4; ++e) {
        dx = xi - cx[e]; dy = yi - cy[e]; dz = zi - cz[e];
        D  = fsqrt(fmaf(dx, dx, fmaf(dy, dy, dz * dz)));
        t  = fmaf(8.f, kv[e], D - 8.f);     // D - 8(1-k)
        s  = fmaf(t, t, s);
    }
    return s;
}

// contact over R contiguous rows, all 4096 columns, K streamed nt + pipelined
template <int R>
__device__ __forceinline__ float contact_rows(const float* __restrict__ K, int row0,
                                              const float* sx, const float* sy,
                                              const float* sz, int tid) {
    float xi[R], yi[R], zi[R];
#pragma unroll
    for (int r = 0; r < R; ++r) {
        xi[r] = sx[row0 + r]; yi[r] = sy[row0 + r]; zi[r] = sz[row0 + r];
    }
    const float* Kt = K + (size_t)row0 * NRES;
    const int j0 = tid << 2;
    float s = 0.f;

    f32x4 va[R], vb[R];
#pragma unroll
    for (int r = 0; r < R; ++r)
        va[r] = __builtin_nontemporal_load((const f32x4*)(Kt + (size_t)r * NRES + j0));

#pragma unroll
    for (int c = 0; c < 4; ++c) {            // 4 column chunks of 1024
        const int jc = j0 + (c << 10);
        f32x4* cur = (c & 1) ? vb : va;
        f32x4* nxt = (c & 1) ? va : vb;
        if (c < 3) {
            const int jn = j0 + ((c + 1) << 10);
#pragma unroll
            for (int r = 0; r < R; ++r)
                nxt[r] = __builtin_nontemporal_load((const f32x4*)(Kt + (size_t)r * NRES + jn));
        }
        const f32x4 cx = *(const f32x4*)&sx[jc];
        const f32x4 cy = *(const f32x4*)&sy[jc];
        const f32x4 cz = *(const f32x4*)&sz[jc];
#pragma unroll
        for (int r = 0; r < R; ++r)
            s = c4(cur[r], cx, cy, cz, xi[r], yi[r], zi[r], s);
    }
    return s;
}

// blocks 0..255: 6 rows @ b*6; blocks 256..767: 5 rows @ 1536+(b-256)*5.
// Per-CU row load = 16 exactly under round-robin dispatch; skew <= 1 row.
__global__ __launch_bounds__(256, 3) void energy_kernel(const float* __restrict__ ca,
                                                        const float* __restrict__ K,
                                                        const int* __restrict__ pairs,
                                                        float4* __restrict__ partial,
                                                        int npairs) {
    __shared__ float sx[NRES], sy[NRES], sz[NRES];   // 48 KB
    __shared__ float red[4][4];
    const int tid = threadIdx.x;
    const int b   = blockIdx.x;

    // preload clash pair indices (resolve during contact streaming)
    const int pbase = b * 256 + tid;
    const i32x2* pairs2 = (const i32x2*)pairs;
    i32x2 pr0 = __builtin_nontemporal_load(&pairs2[pbase]);
    i32x2 pr1 = __builtin_nontemporal_load(&pairs2[pbase + PSTRIDE]);
    const bool has2 = (pbase + 2 * PSTRIDE) < npairs;
    i32x2 pr2 = has2 ? __builtin_nontemporal_load(&pairs2[pbase + 2 * PSTRIDE])
                     : (i32x2){0, 0};

    for (int j = tid; j < NRES; j += 256) {
        sx[j] = ca[3 * j + 0];
        sy[j] = ca[3 * j + 1];
        sz[j] = ca[3 * j + 2];
    }
    __syncthreads();

    // ---------------- contact ----------------
    float contact;
    if (b < 256) contact = contact_rows<6>(K, b * 6, sx, sy, sz, tid);
    else         contact = contact_rows<5>(K, 1536 + (b - 256) * 5, sx, sy, sz, tid);

    // ---------------- clash: preloaded indices, gathers from LDS ----------------
    float clash = 0.f;
    {
        float dx, dy, dz, d, r;
        dx = sx[pr0.x] - sx[pr0.y]; dy = sy[pr0.x] - sy[pr0.y]; dz = sz[pr0.x] - sz[pr0.y];
        d = fsqrt(fmaxf(fmaf(dx, dx, fmaf(dy, dy, dz * dz)), 1e-12f));
        r = fmaxf(3.2f - d, 0.f); clash = fmaf(r, r, clash);

        dx = sx[pr1.x] - sx[pr1.y]; dy = sy[pr1.x] - sy[pr1.y]; dz = sz[pr1.x] - sz[pr1.y];
        d = fsqrt(fmaxf(fmaf(dx, dx, fmaf(dy, dy, dz * dz)), 1e-12f));
        r = fmaxf(3.2f - d, 0.f); clash = fmaf(r, r, clash);

        if (has2) {
            dx = sx[pr2.x] - sx[pr2.y]; dy = sy[pr2.x] - sy[pr2.y]; dz = sz[pr2.x] - sz[pr2.y];
            d = fsqrt(fmaxf(fmaf(dx, dx, fmaf(dy, dy, dz * dz)), 1e-12f));
            r = fmaxf(3.2f - d, 0.f); clash = fmaf(r, r, clash);
        }
    }

    // ---------------- bond + hb: blocks 0..15, from LDS ----------------
    float bond = 0.f, hb = 0.f;
    if (b < HB_BLOCKS) {
        const int i = b * 256 + tid;
        const int n = NRES;

        if (i < n - 1) {
            float dx = sx[i+1]-sx[i], dy = sy[i+1]-sy[i], dz = sz[i+1]-sz[i];
            float d  = sqrtf(fmaf(dx, dx, fmaf(dy, dy, dz * dz)));
            float t  = d - 3.8f;
            bond = t * t;
        }

        if (i < n - 2) {
            float cax = sx[i], cay = sy[i], caz = sz[i];
            float vx = sx[i+1]-cax, vy = sy[i+1]-cay, vz = sz[i+1]-caz;
            float inv = 1.f / (sqrtf(vx*vx + vy*vy + vz*vz) + 1e-8f);
            float ux = vx*inv, uy = vy*inv, uz = vz*inv;

            float upx, upy, upz;
            if (i == 0) { upx = ux; upy = uy; upz = uz; }
            else {
                float wx = cax-sx[i-1], wy = cay-sy[i-1], wz = caz-sz[i-1];
                float inv2 = 1.f / (sqrtf(wx*wx + wy*wy + wz*wz) + 1e-8f);
                upx = wx*inv2; upy = wy*inv2; upz = wz*inv2;
            }

            float vcx = 0.38f*ux,  vcy = 0.38f*uy,  vcz = 0.38f*uz;
            float vnx = -0.38f*upx, vny = -0.38f*upy, vnz = -0.38f*upz;
            float px = vcy*vnz - vcz*vny;
            float py = vcz*vnx - vcx*vnz;
            float pz = vcx*vny - vcy*vnx;
            float pn = sqrtf(px*px + py*py + pz*pz);
            if (pn > 1e-6f) {
                float ipn = 1.f / fmaxf(pn, 1e-12f);
                px *= ipn; py *= ipn; pz *= ipn;
            }
            float ox = cax + vcx + 1.24f*px;
            float oy = cay + vcy + 1.24f*py;
            float oz = caz + vcz + 1.24f*pz;

#pragma unroll
            for (int off = 2; off <= 5; ++off) {
                int jj = i + off;
                if (jj < n) {
                    float cjx = sx[jj], cjy = sy[jj], cjz = sz[jj];
                    float qx = cjx-sx[jj-1], qy = cjy-sy[jj-1], qz = cjz-sz[jj-1];
                    float invq = 1.f / (sqrtf(qx*qx + qy*qy + qz*qz) + 1e-8f);
                    float njx = cjx - 0.38f*qx*invq;
                    float njy = cjy - 0.38f*qy*invq;
                    float njz = cjz - 0.38f*qz*invq;
                    float ddx = ox-njx, ddy = oy-njy, ddz = oz-njz;
                    float d = sqrtf(ddx*ddx + ddy*ddy + ddz*ddz);
                    if (d > 2.5f && d < 3.5f) {
                        float z = (d - 2.95f) * (1.0f / 0.3f);
                        hb -= 0.5f * expf(-z*z);
                    }
                }
            }
        }
    }

    // ---------------- block reduce -> partial[b] ----------------
    float vbo = wave_sum(bond);
    float vcl = wave_sum(clash);
    float vco = wave_sum(contact);
    float vhb = wave_sum(hb);
    const int wave = tid >> 6;
    if ((tid & 63) == 0) {
        red[wave][0] = vbo; red[wave][1] = vcl; red[wave][2] = vco; red[wave][3] = vhb;
    }
    __syncthreads();
    if (tid == 0) {
        float4 o;
        o.x = red[0][0] + red[1][0] + red[2][0] + red[3][0];
        o.y = red[0][1] + red[1][1] + red[2][1] + red[3][1];
        o.z = red[0][2] + red[1][2] + red[2][2] + red[3][2];
        o.w = red[0][3] + red[1][3] + red[2][3] + red[3][3];
        partial[b] = o;
    }
}

// ---- reduce GRID partials, apply weights ----
__global__ __launch_bounds__(256) void finalize_kernel(const float4* __restrict__ partial,
                                                       float* __restrict__ out,
                                                       int n, int npairs) {
    __shared__ float red[4][4];
    const int tid = threadIdx.x;
    float vb = 0.f, vc = 0.f, vk = 0.f, vh = 0.f;
#pragma unroll
    for (int s = 0; s < GRID; s += 256) {
        float4 a = partial[tid + s];
        vb += a.x; vc += a.y; vk += a.z; vh += a.w;
    }
    vb = wave_sum(vb); vc = wave_sum(vc); vk = wave_sum(vk); vh = wave_sum(vh);
    const int wave = tid >> 6;
    if ((tid & 63) == 0) {
        red[wave][0] = vb; red[wave][1] = vc; red[wave][2] = vk; red[wave][3] = vh;
    }
    __syncthreads();
    if (tid == 0) {
        float bond    = red[0][0] + red[1][0] + red[2][0] + red[3][0];
        float clash   = red[0][1] + red[1][1] + red[2][1] + red[3][1];
        float contact = red[0][2] + red[1][2] + red[2][2] + red[3][2];
        float hb      = red[0][3] + red[1][3] + red[2][3] + red[3][3];
        float inv_nn  = 1.f / ((float)n * (float)n);
        out[0] = 30.f * bond / (float)(n - 1)
               + 50.f * clash / (float)npairs
               + 5.f  * contact * inv_nn
               + 4.f  * hb * inv_nn;
    }
}

extern "C" void kernel_launch(void* const* d_in, const int* in_sizes, int n_in,
                              void* d_out, int out_size, void* d_ws, size_t ws_size,
                              hipStream_t stream) {
    const float* ca    = (const float*)d_in[0];
    const float* K     = (const float*)d_in[1];
    const int*   pairs = (const int*)d_in[2];   // int32 on device (x64 disabled)
    float* out = (float*)d_out;
    float4* partial = (float4*)d_ws;            // GRID float4 = 12 KB

    int n      = in_sizes[0] / 3;               // 4096
    int npairs = in_sizes[2] / 2;               // 500000

    energy_kernel<<<GRID, 256, 0, stream>>>(ca, K, pairs, partial, npairs);
    finalize_kernel<<<1, 256, 0, stream>>>(partial, out, n, npairs);
}

// Round 7
// 100.432 us; speedup vs baseline: 1.0634x; 1.0634x over previous
//
#include <hip/hip_runtime.h>
#include <math.h>

#define NRES   4096
#define GRID   768                 // 3 blocks/CU exactly (48KB LDS cap)
#define TROWS  4
#define NTILES (NRES / TROWS)      // 1024 row-tiles; blocks 0..255 take 2 tiles
#define HB_BLOCKS (NRES / 256)     // 16
#define PSTRIDE (GRID * 256)       // 196608

typedef int i32x2 __attribute__((ext_vector_type(2)));

__device__ __forceinline__ float wave_sum(float v) {
#pragma unroll
    for (int off = 32; off > 0; off >>= 1) v += __shfl_down(v, off, 64);
    return v;
}

// raw v_sqrt_f32 (≈1 ulp), skips libm's IEEE fixup sequence
__device__ __forceinline__ float fsqrt(float x) { return __builtin_amdgcn_sqrtf(x); }

// 4 contact terms: one K float4 vs 4 LDS columns
__device__ __forceinline__ float c4(float4 kv, float4 cx, float4 cy, float4 cz,
                                    float xi, float yi, float zi, float s) {
    float dx, dy, dz, D, t;
    dx = xi - cx.x; dy = yi - cy.x; dz = zi - cz.x;
    D  = fsqrt(fmaf(dx, dx, fmaf(dy, dy, dz * dz)));
    t  = fmaf(8.f, kv.x, D - 8.f);   // D - 8(1-k)
    s  = fmaf(t, t, s);

    dx = xi - cx.y; dy = yi - cy.y; dz = zi - cz.y;
    D  = fsqrt(fmaf(dx, dx, fmaf(dy, dy, dz * dz)));
    t  = fmaf(8.f, kv.y, D - 8.f);
    s  = fmaf(t, t, s);

    dx = xi - cx.z; dy = yi - cy.z; dz = zi - cz.z;
    D  = fsqrt(fmaf(dx, dx, fmaf(dy, dy, dz * dz)));
    t  = fmaf(8.f, kv.z, D - 8.f);
    s  = fmaf(t, t, s);

    dx = xi - cx.w; dy = yi - cy.w; dz = zi - cz.w;
    D  = fsqrt(fmaf(dx, dx, fmaf(dy, dy, dz * dz)));
    t  = fmaf(8.f, kv.w, D - 8.f);
    s  = fmaf(t, t, s);
    return s;
}

// All blocks uniform: full ca table in LDS; contact over grid-strided 4-row
// tiles (K streamed with PLAIN loads -> L2/L3 allocate; K is L3-resident after
// the harness restore copy, so many hits). Clash gathers from LDS with
// preloaded indices; blocks 0..15 do bond/hb. Partials -> d_ws, no atomics.
__global__ __launch_bounds__(256, 3) void energy_kernel(const float* __restrict__ ca,
                                                        const float* __restrict__ K,
                                                        const int* __restrict__ pairs,
                                                        float4* __restrict__ partial,
                                                        int npairs) {
    __shared__ float sx[NRES], sy[NRES], sz[NRES];   // 48 KB
    __shared__ float red[4][4];
    const int tid = threadIdx.x;
    const int b   = blockIdx.x;

    // preload clash pair indices (resolve during contact streaming)
    const int pbase = b * 256 + tid;
    const i32x2* pairs2 = (const i32x2*)pairs;
    i32x2 pr0 = pairs2[pbase];
    i32x2 pr1 = pairs2[pbase + PSTRIDE];
    const bool has2 = (pbase + 2 * PSTRIDE) < npairs;
    i32x2 pr2 = has2 ? pairs2[pbase + 2 * PSTRIDE] : (i32x2){0, 0};

    for (int j = tid; j < NRES; j += 256) {
        sx[j] = ca[3 * j + 0];
        sy[j] = ca[3 * j + 1];
        sz[j] = ca[3 * j + 2];
    }
    __syncthreads();

    // ---------------- contact: grid-stride over 4-row tiles ----------------
    float contact = 0.f;
    for (int t = b; t < NTILES; t += GRID) {
        const int rbase = t * TROWS;
        float xi[TROWS], yi[TROWS], zi[TROWS];
#pragma unroll
        for (int r = 0; r < TROWS; ++r) {
            xi[r] = sx[rbase + r]; yi[r] = sy[rbase + r]; zi[r] = sz[rbase + r];
        }

        const float* Kt = K + (size_t)rbase * NRES;
        const int j0 = tid << 2;
        float4 va[TROWS], vb[TROWS];
#pragma unroll
        for (int r = 0; r < TROWS; ++r)
            va[r] = *(const float4*)(Kt + (size_t)r * NRES + j0);

#pragma unroll
        for (int c = 0; c < 4; ++c) {               // 4 column chunks of 1024
            const int jc = j0 + (c << 10);
            float4* cur = (c & 1) ? vb : va;
            float4* nxt = (c & 1) ? va : vb;
            if (c < 3) {
                const int jn = j0 + ((c + 1) << 10);
#pragma unroll
                for (int r = 0; r < TROWS; ++r)
                    nxt[r] = *(const float4*)(Kt + (size_t)r * NRES + jn);
            }
            const float4 cx = *(const float4*)&sx[jc];
            const float4 cy = *(const float4*)&sy[jc];
            const float4 cz = *(const float4*)&sz[jc];
#pragma unroll
            for (int r = 0; r < TROWS; ++r)
                contact = c4(cur[r], cx, cy, cz, xi[r], yi[r], zi[r], contact);
        }
    }

    // ---------------- clash: preloaded indices, gathers from LDS ----------------
    float clash = 0.f;
    {
        float dx, dy, dz, d, r;
        dx = sx[pr0.x] - sx[pr0.y]; dy = sy[pr0.x] - sy[pr0.y]; dz = sz[pr0.x] - sz[pr0.y];
        d = fsqrt(fmaxf(fmaf(dx, dx, fmaf(dy, dy, dz * dz)), 1e-12f));
        r = fmaxf(3.2f - d, 0.f); clash = fmaf(r, r, clash);

        dx = sx[pr1.x] - sx[pr1.y]; dy = sy[pr1.x] - sy[pr1.y]; dz = sz[pr1.x] - sz[pr1.y];
        d = fsqrt(fmaxf(fmaf(dx, dx, fmaf(dy, dy, dz * dz)), 1e-12f));
        r = fmaxf(3.2f - d, 0.f); clash = fmaf(r, r, clash);

        if (has2) {
            dx = sx[pr2.x] - sx[pr2.y]; dy = sy[pr2.x] - sy[pr2.y]; dz = sz[pr2.x] - sz[pr2.y];
            d = fsqrt(fmaxf(fmaf(dx, dx, fmaf(dy, dy, dz * dz)), 1e-12f));
            r = fmaxf(3.2f - d, 0.f); clash = fmaf(r, r, clash);
        }
    }

    // ---------------- bond + hb: blocks 0..15, from LDS ----------------
    float bond = 0.f, hb = 0.f;
    if (b < HB_BLOCKS) {
        const int i = b * 256 + tid;
        const int n = NRES;

        if (i < n - 1) {
            float dx = sx[i+1]-sx[i], dy = sy[i+1]-sy[i], dz = sz[i+1]-sz[i];
            float d  = sqrtf(fmaf(dx, dx, fmaf(dy, dy, dz * dz)));
            float t  = d - 3.8f;
            bond = t * t;
        }

        if (i < n - 2) {
            float cax = sx[i], cay = sy[i], caz = sz[i];
            float vx = sx[i+1]-cax, vy = sy[i+1]-cay, vz = sz[i+1]-caz;
            float inv = 1.f / (sqrtf(vx*vx + vy*vy + vz*vz) + 1e-8f);
            float ux = vx*inv, uy = vy*inv, uz = vz*inv;

            float upx, upy, upz;
            if (i == 0) { upx = ux; upy = uy; upz = uz; }
            else {
                float wx = cax-sx[i-1], wy = cay-sy[i-1], wz = caz-sz[i-1];
                float inv2 = 1.f / (sqrtf(wx*wx + wy*wy + wz*wz) + 1e-8f);
                upx = wx*inv2; upy = wy*inv2; upz = wz*inv2;
            }

            float vcx = 0.38f*ux,  vcy = 0.38f*uy,  vcz = 0.38f*uz;
            float vnx = -0.38f*upx, vny = -0.38f*upy, vnz = -0.38f*upz;
            float px = vcy*vnz - vcz*vny;
            float py = vcz*vnx - vcx*vnz;
            float pz = vcx*vny - vcy*vnx;
            float pn = sqrtf(px*px + py*py + pz*pz);
            if (pn > 1e-6f) {
                float ipn = 1.f / fmaxf(pn, 1e-12f);
                px *= ipn; py *= ipn; pz *= ipn;
            }
            float ox = cax + vcx + 1.24f*px;
            float oy = cay + vcy + 1.24f*py;
            float oz = caz + vcz + 1.24f*pz;

#pragma unroll
            for (int off = 2; off <= 5; ++off) {
                int jj = i + off;
                if (jj < n) {
                    float cjx = sx[jj], cjy = sy[jj], cjz = sz[jj];
                    float qx = cjx-sx[jj-1], qy = cjy-sy[jj-1], qz = cjz-sz[jj-1];
                    float invq = 1.f / (sqrtf(qx*qx + qy*qy + qz*qz) + 1e-8f);
                    float njx = cjx - 0.38f*qx*invq;
                    float njy = cjy - 0.38f*qy*invq;
                    float njz = cjz - 0.38f*qz*invq;
                    float ddx = ox-njx, ddy = oy-njy, ddz = oz-njz;
                    float d = sqrtf(ddx*ddx + ddy*ddy + ddz*ddz);
                    if (d > 2.5f && d < 3.5f) {
                        float z = (d - 2.95f) * (1.0f / 0.3f);
                        hb -= 0.5f * expf(-z*z);
                    }
                }
            }
        }
    }

    // ---------------- block reduce -> partial[b] ----------------
    float vbo = wave_sum(bond);
    float vcl = wave_sum(clash);
    float vco = wave_sum(contact);
    float vhb = wave_sum(hb);
    const int wave = tid >> 6;
    if ((tid & 63) == 0) {
        red[wave][0] = vbo; red[wave][1] = vcl; red[wave][2] = vco; red[wave][3] = vhb;
    }
    __syncthreads();
    if (tid == 0) {
        float4 o;
        o.x = red[0][0] + red[1][0] + red[2][0] + red[3][0];
        o.y = red[0][1] + red[1][1] + red[2][1] + red[3][1];
        o.z = red[0][2] + red[1][2] + red[2][2] + red[3][2];
        o.w = red[0][3] + red[1][3] + red[2][3] + red[3][3];
        partial[b] = o;
    }
}

// ---- reduce GRID partials, apply weights ----
__global__ __launch_bounds__(256) void finalize_kernel(const float4* __restrict__ partial,
                                                       float* __restrict__ out,
                                                       int n, int npairs) {
    __shared__ float red[4][4];
    const int tid = threadIdx.x;
    float vb = 0.f, vc = 0.f, vk = 0.f, vh = 0.f;
#pragma unroll
    for (int s = 0; s < GRID; s += 256) {
        float4 a = partial[tid + s];
        vb += a.x; vc += a.y; vk += a.z; vh += a.w;
    }
    vb = wave_sum(vb); vc = wave_sum(vc); vk = wave_sum(vk); vh = wave_sum(vh);
    const int wave = tid >> 6;
    if ((tid & 63) == 0) {
        red[wave][0] = vb; red[wave][1] = vc; red[wave][2] = vk; red[wave][3] = vh;
    }
    __syncthreads();
    if (tid == 0) {
        float bond    = red[0][0] + red[1][0] + red[2][0] + red[3][0];
        float clash   = red[0][1] + red[1][1] + red[2][1] + red[3][1];
        float contact = red[0][2] + red[1][2] + red[2][2] + red[3][2];
        float hb      = red[0][3] + red[1][3] + red[2][3] + red[3][3];
        float inv_nn  = 1.f / ((float)n * (float)n);
        out[0] = 30.f * bond / (float)(n - 1)
               + 50.f * clash / (float)npairs
               + 5.f  * contact * inv_nn
               + 4.f  * hb * inv_nn;
    }
}

extern "C" void kernel_launch(void* const* d_in, const int* in_sizes, int n_in,
                              void* d_out, int out_size, void* d_ws, size_t ws_size,
                              hipStream_t stream) {
    const float* ca    = (const float*)d_in[0];
    const float* K     = (const float*)d_in[1];
    const int*   pairs = (const int*)d_in[2];   // int32 on device (x64 disabled)
    float* out = (float*)d_out;
    float4* partial = (float4*)d_ws;            // GRID float4 = 12 KB

    int n      = in_sizes[0] / 3;               // 4096
    int npairs = in_sizes[2] / 2;               // 500000

    energy_kernel<<<GRID, 256, 0, stream>>>(ca, K, pairs, partial, npairs);
    finalize_kernel<<<1, 256, 0, stream>>>(partial, out, n, npairs);
}